// Round 12
// baseline (257.609 us; speedup 1.0000x reference)
//
#include <hip/hip_runtime.h>

typedef __bf16 bf16;
typedef __bf16 bf16x8 __attribute__((ext_vector_type(8)));
typedef float f32x4 __attribute__((ext_vector_type(4)));

__device__ __forceinline__ f32x4 mfma16(bf16x8 a, bf16x8 b, f32x4 c) {
  return __builtin_amdgcn_mfma_f32_16x16x32_bf16(a, b, c, 0, 0, 0);
}

// async global->LDS 16B; LDS dest is wave-uniform base, lane l writes base+l*16.
__device__ __forceinline__ void gload16(const void* g, void* l) {
  __builtin_amdgcn_global_load_lds(
      (const __attribute__((address_space(1))) void*)g,
      (__attribute__((address_space(3))) void*)(uint32_t)(size_t)l, 16, 0, 0);
}

__device__ __forceinline__ bf16x8 cvt8(float4 a, float4 b) {
  bf16x8 r;
  r[0] = (bf16)a.x; r[1] = (bf16)a.y; r[2] = (bf16)a.z; r[3] = (bf16)a.w;
  r[4] = (bf16)b.x; r[5] = (bf16)b.y; r[6] = (bf16)b.z; r[7] = (bf16)b.w;
  return r;
}

// ---------------- gating: writes B in MFMA-panel layout ----------------
// Panel: row-group rg=b>>4 (64KB); byte rg*65536 + s*1024 + lane*16 = granule
// q=4s+(lane>>4) of row rg*16+(lane&15).
__global__ __launch_bounds__(256) void gating_kernel(
    const float* __restrict__ x, const float* __restrict__ gw,
    const float* __restrict__ gb, bf16* __restrict__ xgbP,
    float* __restrict__ gbuf) {
  const int b = blockIdx.x, tid = threadIdx.x;
  __shared__ float xs[256];
  __shared__ float gs[8];
  xs[tid] = x[b * 256 + tid];
  __syncthreads();
  if (tid < 8) {
    float acc = gb[tid];
    for (int i = 0; i < 256; ++i) acc += xs[i] * gw[i * 8 + tid];
    gs[tid] = acc;
  }
  __syncthreads();
  if (tid == 0) {
    float m = gs[0];
    for (int l = 1; l < 8; ++l) m = fmaxf(m, gs[l]);
    float s = 0.f, e[8];
    for (int l = 0; l < 8; ++l) { e[l] = expf(gs[l] - m); s += e[l]; }
    float inv = 1.f / s;
    for (int l = 0; l < 8; ++l) gs[l] = e[l] * inv;
  }
  __syncthreads();
  if (tid < 8) gbuf[b * 8 + tid] = gs[tid];
  float xv = xs[tid];
  bf16x8 r;
#pragma unroll
  for (int j = 0; j < 8; ++j) r[j] = (bf16)(xv * gs[j]);
  size_t off = (size_t)(b >> 4) * 65536 + (size_t)(tid >> 2) * 1024 +
               (size_t)(((tid & 3) * 16 + (b & 15)) * 16);
  *(bf16x8*)((char*)xgbP + off) = r;
}

// ---------------- merged weight transform ----------------
template <int CIN, int COUT, int COUTP>
__device__ __forceinline__ void cw_one(const float* __restrict__ w,
                                       bf16* __restrict__ wp, int idx) {
  constexpr int K = 4 * CIN;
  int ic = idx & (CIN - 1);
  int t = (idx / CIN) & 3;
  int oc = (idx / K) % COUTP;
  int p = idx / (K * COUTP);
  bf16 v = (bf16)0.f;
  if (oc < COUT) {
    int py = p >> 1, px = p & 1, tyi = t >> 1, txi = t & 1;
    int ky = py == 0 ? (tyi ? 3 : 1) : (tyi ? 2 : 0);
    int kx = px == 0 ? (txi ? 3 : 1) : (txi ? 2 : 0);
    v = (bf16)w[((ic * COUT + oc) * 4 + ky) * 4 + kx];
  }
  wp[idx] = v;
}

__global__ __launch_bounds__(256) void convert_w_all(
    const float* __restrict__ w1, bf16* __restrict__ w1p,
    const float* __restrict__ w2, bf16* __restrict__ w2p,
    const float* __restrict__ w3, bf16* __restrict__ w3p) {
  int idx = blockIdx.x * 256 + threadIdx.x;
  if (idx < 131072) cw_one<128, 64, 64>(w1, w1p, idx);
  else if (idx < 163840) cw_one<64, 32, 32>(w2, w2p, idx - 131072);
  else if (idx < 172032) cw_one<32, 3, 16>(w3, w3p, idx - 163840);
}

// ---------------- merged halo zero ----------------
template <int HP, int WP, int C>
__device__ __forceinline__ void bz_one(bf16* __restrict__ buf, int idx) {
  constexpr int NCELL = 2 * WP + 2 * (HP - 2);
  constexpr int C8 = C / 8;
  int c8 = idx % C8;
  int rem = idx / C8;
  int cell = rem % NCELL;
  int b = rem / NCELL;
  int y, x;
  if (cell < WP) { y = 0; x = cell; }
  else if (cell < 2 * WP) { y = HP - 1; x = cell - WP; }
  else { int r2 = cell - 2 * WP; y = 1 + (r2 >> 1); x = (r2 & 1) ? WP - 1 : 0; }
  bf16x8 z = {};
  *(bf16x8*)(buf + ((size_t)(b * HP + y) * WP + x) * C + c8 * 8) = z;
}

__global__ __launch_bounds__(256) void border_zero_all(
    bf16* __restrict__ h0t, bf16* __restrict__ h1, bf16* __restrict__ h2) {
  int idx = blockIdx.x * 256 + threadIdx.x;
  if (idx < 147456) bz_one<10, 10, 128>(h0t, idx);
  else if (idx < 286720) bz_one<18, 18, 64>(h1, idx - 147456);
  else if (idx < 421888) bz_one<34, 34, 32>(h2, idx - 286720);
}

// ---------------- fused ME GEMM: max-TLP, zero LDS, zero barriers ----------------
// C[o,b] = bf16(pw[o,:]) . xgb[b,:] + dot(g[b],pb[o]).
// 2048 blocks x 256 thr (4 waves) = 8 blocks/CU = 32 waves/CU. Wave = 16M x 16N,
// acc = 4 VGPR. Work map XCD-chunked: work=(bid&7)*256+(bid>>3); m=work>>2, n=work&3
// so an M-tile's 4 N-siblings run back-to-back on one XCD (A rows hit that XCD's L2).
// A: fragment-direct f32 (4 lanes x 32B = full 128B line); B: sequential panel stream.
__global__ __launch_bounds__(256, 8) void me_gemm_kernel(
    const float* __restrict__ pw, const bf16* __restrict__ xgbP,
    const float* __restrict__ pb, const float* __restrict__ gbuf,
    bf16* __restrict__ h0t) {
  const int tid = threadIdx.x, wv = tid >> 6, l = tid & 63;
  const int lr = l & 15, lkg = l >> 4;
  const int work = (blockIdx.x & 7) * 256 + (blockIdx.x >> 3);
  const int M0 = (work >> 2) * 16;
  const int rg = (work & 3) * 4 + wv;  // B row-group 0..15

  const float* pA = pw + (size_t)(M0 + lr) * 2048 + lkg * 8;
  const char* pB = (const char*)xgbP + (size_t)rg * 65536 + l * 16;

  f32x4 acc = {};
#pragma unroll 4
  for (int s = 0; s < 64; ++s) {
    float4 a0 = *(const float4*)(pA + s * 32);
    float4 a1 = *(const float4*)(pA + s * 32 + 4);
    bf16x8 av = cvt8(a0, a1);
    bf16x8 bv = *(const bf16x8*)(pB + s * 1024);
    acc = mfma16(av, bv, acc);
  }

  // epilogue: + dot(g[b], pb[o]) -> h0t padded channels-last
  const int b = rg * 16 + lr;
  const float* gr = gbuf + b * 8;
  float g0 = gr[0], g1 = gr[1], g2 = gr[2], g3 = gr[3];
  float g4 = gr[4], g5 = gr[5], g6 = gr[6], g7 = gr[7];
#pragma unroll
  for (int r = 0; r < 4; ++r) {
    int o = M0 + lkg * 4 + r;
    float4 p0 = *(const float4*)(pb + o * 8);
    float4 p1 = *(const float4*)(pb + o * 8 + 4);
    float bias = g0 * p0.x + g1 * p0.y + g2 * p0.z + g3 * p0.w +
                 g4 * p1.x + g5 * p1.y + g6 * p1.z + g7 * p1.w;
    int cch = o >> 6, y = (o >> 3) & 7, xx = o & 7;
    h0t[((size_t)(b * 10 + y + 1) * 10 + xx + 1) * 128 + cch] = (bf16)(acc[r] + bias);
  }
}

// ---------------- conv-transpose: fused 4-parity (p inside K-loop), input staged once --
// Block = YB output-row slab of one image, all 4 parities; wave = 16 rows x 16*NF oc.
// Per kk: 4 av + 4*NF bv loads -> 4*NF independent MFMA chains (ILP), zero barriers
// after the single staging sync.
template <int CIN, int H, int YB, int COUTP, int WM, int NF, int SWM, int INIT,
          bool RELU, bool F32OUT, int SIN_SZ>
__global__ __launch_bounds__(256, 4) void convt_kernel(
    const bf16* __restrict__ in, const bf16* __restrict__ wp,
    const float* __restrict__ bias, bf16* __restrict__ out,
    float* __restrict__ fout) {
  constexpr int W = H, WROW = W + 2, ROWB = CIN * 2, GRS = ROWB / 16;
  constexpr int LGR = (GRS == 16) ? 4 : (GRS == 8) ? 3 : 2;
  constexpr int LW = (W == 8) ? 3 : (W == 16) ? 4 : 5;
  constexpr int K = 4 * CIN;
  constexpr int CHUNKS = (YB + 2) * WROW * GRS;
  __shared__ char sIn[SIN_SZ];

  const int tid = threadIdx.x, wv = tid >> 6, l = tid & 63;
  const int nyb = H / YB;
  const int img = blockIdx.x / nyb, y0 = (blockIdx.x % nyb) * YB;

#pragma unroll
  for (int it = 0; it < INIT; ++it) {
    int t = it * 256 + tid;
    int tc = t < CHUNKS ? t : CHUNKS - 1;
    int pix = tc >> LGR, cc = tc & (GRS - 1);
    int ly = pix / WROW, lx = pix % WROW;
    int sb = (cc * 16) ^ ((pix & SWM) << 4);
    gload16(in + ((size_t)((img * (H + 2) + y0 + ly) * (W + 2) + lx)) * CIN + (sb >> 1),
            sIn + it * 4096 + wv * 1024);
  }
  __syncthreads();

  const int lr = l & 15, lkg = l >> 4;
  const int wm = wv & (WM - 1), wn = wv / WM;
  const int r0 = wm * 16 + lr;
  const int pcen = ((r0 >> LW) + 1) * WROW + (r0 & (W - 1)) + 1;

  f32x4 acc[4][NF] = {};
#pragma unroll 2
  for (int kk = 0; kk < K; kk += 32) {
    const int t4 = kk / CIN;
    const int tyi = t4 >> 1, txi = t4 & 1;
    const int icb = (kk % CIN) * 2 + lkg * 16;
    bf16x8 av[4], bv[4][NF];
#pragma unroll
    for (int p = 0; p < 4; ++p) {
      const int py = p >> 1, px = p & 1;
      const int dy = (py == 0) ? (tyi ? -1 : 0) : (tyi ? 0 : 1);
      const int dx = (px == 0) ? (txi ? -1 : 0) : (txi ? 0 : 1);
      int pixd = pcen + dy * WROW + dx;
      av[p] = *(const bf16x8*)(sIn + pixd * ROWB + (icb ^ ((pixd & SWM) << 4)));
#pragma unroll
      for (int n = 0; n < NF; ++n) {
        int oc = (wn * NF + n) * 16 + lr;
        bv[p][n] = *(const bf16x8*)(wp + (size_t)(p * COUTP + oc) * K + kk + lkg * 8);
      }
    }
#pragma unroll
    for (int p = 0; p < 4; ++p)
#pragma unroll
      for (int n = 0; n < NF; ++n) acc[p][n] = mfma16(av[p], bv[p][n], acc[p][n]);
  }

#pragma unroll
  for (int p = 0; p < 4; ++p) {
    const int py = p >> 1, px = p & 1;
#pragma unroll
    for (int r4 = 0; r4 < 4; ++r4) {
      int r = wm * 16 + lkg * 4 + r4;
      int yy = r >> LW, xx = r & (W - 1);
      int oy = 2 * (y0 + yy) + py, ox = 2 * xx + px;
#pragma unroll
      for (int n = 0; n < NF; ++n) {
        int oc = (wn * NF + n) * 16 + lr;
        float v = acc[p][n][r4];
        if constexpr (F32OUT) {
          if (oc < 3) fout[((size_t)(img * 3 + oc) * (2 * H) + oy) * (2 * H) + ox] = v + bias[oc];
        } else {
          v += bias[oc];
          if constexpr (RELU) v = fmaxf(v, 0.f);
          out[((size_t)(img * (2 * H + 2) + oy + 1) * (2 * H + 2) + ox + 1) * COUTP + oc] = (bf16)v;
        }
      }
    }
  }
}

// ---------------- launch ----------------
extern "C" void kernel_launch(void* const* d_in, const int* in_sizes, int n_in,
                              void* d_out, int out_size, void* d_ws, size_t ws_size,
                              hipStream_t stream) {
  const float* x  = (const float*)d_in[0];
  const float* gw = (const float*)d_in[1];
  const float* gb = (const float*)d_in[2];
  const float* pw = (const float*)d_in[3];
  const float* pb = (const float*)d_in[4];
  const float* w1 = (const float*)d_in[5];
  const float* b1 = (const float*)d_in[6];
  const float* w2 = (const float*)d_in[7];
  const float* b2 = (const float*)d_in[8];
  const float* w3 = (const float*)d_in[9];
  const float* b3 = (const float*)d_in[10];
  float* outp = (float*)d_out;

  char* ws = (char*)d_ws;
  bf16*  xgbP = (bf16*)(ws + 0);          // 1,048,576 (panel layout)
  float* gbuf = (float*)(ws + 1048576);   // 8,192
  bf16*  h0t  = (bf16*)(ws + 1056768);    // 6,553,600
  bf16*  w1p  = (bf16*)(ws + 7610368);    // 262,144
  bf16*  h1   = (bf16*)(ws + 7872512);    // 10,616,832
  bf16*  w2p  = (bf16*)(ws + 18489344);   // 65,536
  bf16*  h2   = (bf16*)(ws + 18554880);   // 18,939,904
  bf16*  w3p  = (bf16*)(ws + 37494784);   // 16,384

  border_zero_all<<<1648, 256, 0, stream>>>(h0t, h1, h2);
  gating_kernel<<<256, 256, 0, stream>>>(x, gw, gb, xgbP, gbuf);
  convert_w_all<<<672, 256, 0, stream>>>(w1, w1p, w2, w2p, w3, w3p);

  me_gemm_kernel<<<2048, 256, 0, stream>>>(pw, xgbP, pb, gbuf, h0t);

  // conv1: YB=2 -> 1024 blocks (4/CU); WM=1: wave=16 rows x 16 oc, 4 wn-groups
  convt_kernel<128, 8, 2, 64, 1, 1, 7, 3, true, false, 12288>
      <<<1024, 256, 0, stream>>>(h0t, w1p, b1, h1, nullptr);
  // conv2: YB=2 -> 2048 blocks (8/CU); WM=2: 32 rows, 2 wn-groups x 16 oc
  convt_kernel<64, 16, 2, 32, 2, 1, 7, 3, true, false, 12288>
      <<<2048, 256, 0, stream>>>(h1, w2p, b2, h2, nullptr);
  // conv3: YB=2 -> 4096 blocks; WM=4: 64 rows, 1 wn-group x 16 oc
  convt_kernel<32, 32, 2, 16, 4, 1, 3, 3, false, true, 12288>
      <<<4096, 256, 0, stream>>>(h2, w3p, b3, nullptr, outp);
}

// Round 13
// 126.017 us; speedup vs baseline: 2.0442x; 2.0442x over previous
//
#include <hip/hip_runtime.h>

typedef __bf16 bf16;
typedef __bf16 bf16x8 __attribute__((ext_vector_type(8)));
typedef float f32x4 __attribute__((ext_vector_type(4)));

__device__ __forceinline__ f32x4 mfma16(bf16x8 a, bf16x8 b, f32x4 c) {
  return __builtin_amdgcn_mfma_f32_16x16x32_bf16(a, b, c, 0, 0, 0);
}

// async global->LDS 16B; LDS dest is wave-uniform base, lane l writes base+l*16.
__device__ __forceinline__ void gload16(const void* g, void* l) {
  __builtin_amdgcn_global_load_lds(
      (const __attribute__((address_space(1))) void*)g,
      (__attribute__((address_space(3))) void*)(uint32_t)(size_t)l, 16, 0, 0);
}

__device__ __forceinline__ bf16x8 cvt8(float4 a, float4 b) {
  bf16x8 r;
  r[0] = (bf16)a.x; r[1] = (bf16)a.y; r[2] = (bf16)a.z; r[3] = (bf16)a.w;
  r[4] = (bf16)b.x; r[5] = (bf16)b.y; r[6] = (bf16)b.z; r[7] = (bf16)b.w;
  return r;
}

// ---------------- gating: writes B in MFMA-panel layout ----------------
// Panel: row-group rg=b>>4 (64KB); byte rg*65536 + s*1024 + lane*16 = granule
// q=4s+(lane>>4) of row rg*16+(lane&15).
__global__ __launch_bounds__(256) void gating_kernel(
    const float* __restrict__ x, const float* __restrict__ gw,
    const float* __restrict__ gb, bf16* __restrict__ xgbP,
    float* __restrict__ gbuf) {
  const int b = blockIdx.x, tid = threadIdx.x;
  __shared__ float xs[256];
  __shared__ float gs[8];
  xs[tid] = x[b * 256 + tid];
  __syncthreads();
  if (tid < 8) {
    float acc = gb[tid];
    for (int i = 0; i < 256; ++i) acc += xs[i] * gw[i * 8 + tid];
    gs[tid] = acc;
  }
  __syncthreads();
  if (tid == 0) {
    float m = gs[0];
    for (int l = 1; l < 8; ++l) m = fmaxf(m, gs[l]);
    float s = 0.f, e[8];
    for (int l = 0; l < 8; ++l) { e[l] = expf(gs[l] - m); s += e[l]; }
    float inv = 1.f / s;
    for (int l = 0; l < 8; ++l) gs[l] = e[l] * inv;
  }
  __syncthreads();
  if (tid < 8) gbuf[b * 8 + tid] = gs[tid];
  float xv = xs[tid];
  bf16x8 r;
#pragma unroll
  for (int j = 0; j < 8; ++j) r[j] = (bf16)(xv * gs[j]);
  size_t off = (size_t)(b >> 4) * 65536 + (size_t)(tid >> 2) * 1024 +
               (size_t)(((tid & 3) * 16 + (b & 15)) * 16);
  *(bf16x8*)((char*)xgbP + off) = r;
}

// ---------------- merged weight transform ----------------
template <int CIN, int COUT, int COUTP>
__device__ __forceinline__ void cw_one(const float* __restrict__ w,
                                       bf16* __restrict__ wp, int idx) {
  constexpr int K = 4 * CIN;
  int ic = idx & (CIN - 1);
  int t = (idx / CIN) & 3;
  int oc = (idx / K) % COUTP;
  int p = idx / (K * COUTP);
  bf16 v = (bf16)0.f;
  if (oc < COUT) {
    int py = p >> 1, px = p & 1, tyi = t >> 1, txi = t & 1;
    int ky = py == 0 ? (tyi ? 3 : 1) : (tyi ? 2 : 0);
    int kx = px == 0 ? (txi ? 3 : 1) : (txi ? 2 : 0);
    v = (bf16)w[((ic * COUT + oc) * 4 + ky) * 4 + kx];
  }
  wp[idx] = v;
}

__global__ __launch_bounds__(256) void convert_w_all(
    const float* __restrict__ w1, bf16* __restrict__ w1p,
    const float* __restrict__ w2, bf16* __restrict__ w2p,
    const float* __restrict__ w3, bf16* __restrict__ w3p) {
  int idx = blockIdx.x * 256 + threadIdx.x;
  if (idx < 131072) cw_one<128, 64, 64>(w1, w1p, idx);
  else if (idx < 163840) cw_one<64, 32, 32>(w2, w2p, idx - 131072);
  else if (idx < 172032) cw_one<32, 3, 16>(w3, w3p, idx - 163840);
}

// ---------------- merged halo zero ----------------
template <int HP, int WP, int C>
__device__ __forceinline__ void bz_one(bf16* __restrict__ buf, int idx) {
  constexpr int NCELL = 2 * WP + 2 * (HP - 2);
  constexpr int C8 = C / 8;
  int c8 = idx % C8;
  int rem = idx / C8;
  int cell = rem % NCELL;
  int b = rem / NCELL;
  int y, x;
  if (cell < WP) { y = 0; x = cell; }
  else if (cell < 2 * WP) { y = HP - 1; x = cell - WP; }
  else { int r2 = cell - 2 * WP; y = 1 + (r2 >> 1); x = (r2 & 1) ? WP - 1 : 0; }
  bf16x8 z = {};
  *(bf16x8*)(buf + ((size_t)(b * HP + y) * WP + x) * C + c8 * 8) = z;
}

__global__ __launch_bounds__(256) void border_zero_all(
    bf16* __restrict__ h0t, bf16* __restrict__ h1, bf16* __restrict__ h2) {
  int idx = blockIdx.x * 256 + threadIdx.x;
  if (idx < 147456) bz_one<10, 10, 128>(h0t, idx);
  else if (idx < 286720) bz_one<18, 18, 64>(h1, idx - 147456);
  else if (idx < 421888) bz_one<34, 34, 32>(h2, idx - 286720);
}

// ---------------- fused ME GEMM (r9-best, verbatim): BM=16, 2 blocks/CU -------------
// C[o,b] = bf16(pw[o,:]) . xgb[b,:] + dot(g[b],pb[o]).
// 512 blocks (2/CU) x 512 thr (8 waves). Block stages its 16 pw rows (f32->bf16
// in-register) into 64KB LDS once; ONE barrier; barrier-free K-loop: A from
// swizzled LDS, B from panel-layout xgbP (16B/lane sequential, L2-hot).
__global__ __launch_bounds__(512) void me_gemm_kernel(
    const float* __restrict__ pw, const bf16* __restrict__ xgbP,
    const float* __restrict__ pb, const float* __restrict__ gbuf,
    bf16* __restrict__ h0t) {
  __shared__ char sA[65536];
  const int tid = threadIdx.x, wv = tid >> 6, l = tid & 63;
  const int lr = l & 15, lkg = l >> 4;
  const int M0 = blockIdx.x * 16;

  // ---- stage A: pw f32 -> bf16 swizzled LDS (4096 x 16B granules) ----
#pragma unroll
  for (int it = 0; it < 8; ++it) {
    int g = it * 512 + tid;
    int kt = g >> 7, rem = g & 127;
    int row = rem >> 3, ig = rem & 7;
    const float* src = pw + (size_t)(M0 + row) * 2048 + kt * 64 + ig * 8;
    float4 v0 = *(const float4*)src;
    float4 v1 = *(const float4*)(src + 4);
    int L = kt * 2048 + row * 128 + ((ig * 16) ^ ((row & 7) << 4));
    *(bf16x8*)(sA + L) = cvt8(v0, v1);
  }
  __syncthreads();

  // A read offsets: row = lr, granule = ks*4+lkg
  int aoff[2];
#pragma unroll
  for (int ks = 0; ks < 2; ++ks)
    aoff[ks] = lr * 128 + (((ks * 4 + lkg) * 16) ^ ((lr & 7) << 4));

  // B panel: wave wv streams row-groups 2wv, 2wv+1; 16B/lane, coalesced
  const char* pB0 = (const char*)xgbP + (size_t)(2 * wv) * 65536 + l * 16;
  const char* pB1 = (const char*)xgbP + (size_t)(2 * wv + 1) * 65536 + l * 16;

  f32x4 acc[2] = {};
#pragma unroll 8
  for (int s = 0; s < 64; ++s) {  // 32-K steps
    const int kt = s >> 1, ks = s & 1;
    const char* base = sA + kt * 2048;
    bf16x8 a0 = *(const bf16x8*)(base + aoff[ks]);
    bf16x8 b0 = *(const bf16x8*)(pB0 + s * 1024);
    bf16x8 b1 = *(const bf16x8*)(pB1 + s * 1024);
    acc[0] = mfma16(a0, b0, acc[0]);
    acc[1] = mfma16(a0, b1, acc[1]);
  }

  // epilogue: + dot(g[b], pb[o]) -> h0t padded channels-last
  float4 g0[2], g1[2];
#pragma unroll
  for (int n = 0; n < 2; ++n) {
    int b = wv * 32 + n * 16 + lr;
    g0[n] = *(const float4*)(gbuf + b * 8);
    g1[n] = *(const float4*)(gbuf + b * 8 + 4);
  }
#pragma unroll
  for (int r = 0; r < 4; ++r) {
    int o = M0 + lkg * 4 + r;
    float4 p0 = *(const float4*)(pb + o * 8);
    float4 p1 = *(const float4*)(pb + o * 8 + 4);
    int cch = o >> 6, y = (o >> 3) & 7, xx = o & 7;
#pragma unroll
    for (int n = 0; n < 2; ++n) {
      int b = wv * 32 + n * 16 + lr;
      float bias = g0[n].x * p0.x + g0[n].y * p0.y + g0[n].z * p0.z + g0[n].w * p0.w +
                   g1[n].x * p1.x + g1[n].y * p1.y + g1[n].z * p1.z + g1[n].w * p1.w;
      h0t[((size_t)(b * 10 + y + 1) * 10 + xx + 1) * 128 + cch] = (bf16)(acc[n][r] + bias);
    }
  }
}

// ---------------- conv-transpose (r11-best, verbatim): fused 4-parity, YB=4 ---------
template <int CIN, int H, int YB, int COUTP, int WM, int NF, int SWM, int INIT,
          bool RELU, bool F32OUT, int SIN_SZ>
__global__ __launch_bounds__(256) void convt_kernel(
    const bf16* __restrict__ in, const bf16* __restrict__ wp,
    const float* __restrict__ bias, bf16* __restrict__ out,
    float* __restrict__ fout) {
  constexpr int W = H, WROW = W + 2, ROWB = CIN * 2, GRS = ROWB / 16;
  constexpr int LGR = (GRS == 16) ? 4 : (GRS == 8) ? 3 : 2;
  constexpr int LW = (W == 8) ? 3 : (W == 16) ? 4 : 5;
  constexpr int K = 4 * CIN;
  constexpr int CHUNKS = (YB + 2) * WROW * GRS;
  __shared__ char sIn[SIN_SZ];

  const int tid = threadIdx.x, wv = tid >> 6, l = tid & 63;
  const int nyb = H / YB;
  const int img = blockIdx.x / nyb, y0 = (blockIdx.x % nyb) * YB;

#pragma unroll
  for (int it = 0; it < INIT; ++it) {
    int t = it * 256 + tid;
    int tc = t < CHUNKS ? t : CHUNKS - 1;
    int pix = tc >> LGR, cc = tc & (GRS - 1);
    int ly = pix / WROW, lx = pix % WROW;
    int sb = (cc * 16) ^ ((pix & SWM) << 4);
    gload16(in + ((size_t)((img * (H + 2) + y0 + ly) * (W + 2) + lx)) * CIN + (sb >> 1),
            sIn + it * 4096 + wv * 1024);
  }
  __syncthreads();

  const int lr = l & 15, lkg = l >> 4;
  const int wm = wv & (WM - 1), wn = wv / WM;
  int pcen[2];
#pragma unroll
  for (int m = 0; m < 2; ++m) {
    int r = wm * 32 + m * 16 + lr;
    pcen[m] = ((r >> LW) + 1) * WROW + (r & (W - 1)) + 1;
  }

  f32x4 acc[4][2][NF] = {};
#pragma unroll
  for (int p = 0; p < 4; ++p) {
    const int py = p >> 1, px = p & 1;
#pragma unroll 4
    for (int kk = 0; kk < K; kk += 32) {
      const int t4 = kk / CIN;
      const int tyi = t4 >> 1, txi = t4 & 1;
      const int dy = (py == 0) ? (tyi ? -1 : 0) : (tyi ? 0 : 1);
      const int dx = (px == 0) ? (txi ? -1 : 0) : (txi ? 0 : 1);
      const int icb = (kk % CIN) * 2 + lkg * 16;
      bf16x8 av[2], bv[NF];
#pragma unroll
      for (int m = 0; m < 2; ++m) {
        int pixd = pcen[m] + dy * WROW + dx;
        av[m] = *(const bf16x8*)(sIn + pixd * ROWB + (icb ^ ((pixd & SWM) << 4)));
      }
#pragma unroll
      for (int n = 0; n < NF; ++n) {
        int oc = (wn * NF + n) * 16 + lr;
        bv[n] = *(const bf16x8*)(wp + (size_t)(p * COUTP + oc) * K + kk + lkg * 8);
      }
#pragma unroll
      for (int m = 0; m < 2; ++m)
#pragma unroll
        for (int n = 0; n < NF; ++n) acc[p][m][n] = mfma16(av[m], bv[n], acc[p][m][n]);
    }
  }

#pragma unroll
  for (int p = 0; p < 4; ++p) {
    const int py = p >> 1, px = p & 1;
#pragma unroll
    for (int m = 0; m < 2; ++m)
#pragma unroll
      for (int r4 = 0; r4 < 4; ++r4) {
        int r = wm * 32 + m * 16 + lkg * 4 + r4;
        int yy = r >> LW, xx = r & (W - 1);
        int oy = 2 * (y0 + yy) + py, ox = 2 * xx + px;
#pragma unroll
        for (int n = 0; n < NF; ++n) {
          int oc = (wn * NF + n) * 16 + lr;
          float v = acc[p][m][n][r4];
          if constexpr (F32OUT) {
            if (oc < 3) fout[((size_t)(img * 3 + oc) * (2 * H) + oy) * (2 * H) + ox] = v + bias[oc];
          } else {
            v += bias[oc];
            if constexpr (RELU) v = fmaxf(v, 0.f);
            out[((size_t)(img * (2 * H + 2) + oy + 1) * (2 * H + 2) + ox + 1) * COUTP + oc] = (bf16)v;
          }
        }
      }
  }
}

// ---------------- launch ----------------
extern "C" void kernel_launch(void* const* d_in, const int* in_sizes, int n_in,
                              void* d_out, int out_size, void* d_ws, size_t ws_size,
                              hipStream_t stream) {
  const float* x  = (const float*)d_in[0];
  const float* gw = (const float*)d_in[1];
  const float* gb = (const float*)d_in[2];
  const float* pw = (const float*)d_in[3];
  const float* pb = (const float*)d_in[4];
  const float* w1 = (const float*)d_in[5];
  const float* b1 = (const float*)d_in[6];
  const float* w2 = (const float*)d_in[7];
  const float* b2 = (const float*)d_in[8];
  const float* w3 = (const float*)d_in[9];
  const float* b3 = (const float*)d_in[10];
  float* outp = (float*)d_out;

  char* ws = (char*)d_ws;
  bf16*  xgbP = (bf16*)(ws + 0);          // 1,048,576 (panel layout)
  float* gbuf = (float*)(ws + 1048576);   // 8,192
  bf16*  h0t  = (bf16*)(ws + 1056768);    // 6,553,600
  bf16*  w1p  = (bf16*)(ws + 7610368);    // 262,144
  bf16*  h1   = (bf16*)(ws + 7872512);    // 10,616,832
  bf16*  w2p  = (bf16*)(ws + 18489344);   // 65,536
  bf16*  h2   = (bf16*)(ws + 18554880);   // 18,939,904
  bf16*  w3p  = (bf16*)(ws + 37494784);   // 16,384

  border_zero_all<<<1648, 256, 0, stream>>>(h0t, h1, h2);
  gating_kernel<<<256, 256, 0, stream>>>(x, gw, gb, xgbP, gbuf);
  convert_w_all<<<672, 256, 0, stream>>>(w1, w1p, w2, w2p, w3, w3p);

  me_gemm_kernel<<<512, 512, 0, stream>>>(pw, xgbP, pb, gbuf, h0t);

  // conv1: YB=4 -> 512 blocks; WM=1 (32 rows), wn=wv -> 64 oc
  convt_kernel<128, 8, 4, 64, 1, 1, 7, 4, true, false, 16384>
      <<<512, 256, 0, stream>>>(h0t, w1p, b1, h1, nullptr);
  // conv2: YB=4 -> 1024 blocks; WM=2 (64 rows), 2 wn-groups -> 32 oc
  convt_kernel<64, 16, 4, 32, 2, 1, 7, 4, true, false, 16384>
      <<<1024, 256, 0, stream>>>(h1, w2p, b2, h2, nullptr);
  // conv3: YB=4 -> 2048 blocks; WM=4 (128 rows), 1 wn-group -> 16 oc
  convt_kernel<32, 32, 4, 16, 4, 1, 3, 4, false, true, 16384>
      <<<2048, 256, 0, stream>>>(h2, w3p, b3, nullptr, outp);
}

// Round 14
// 100.706 us; speedup vs baseline: 2.5580x; 1.2513x over previous
//
#include <hip/hip_runtime.h>

typedef __bf16 bf16;
typedef __bf16 bf16x8 __attribute__((ext_vector_type(8)));
typedef float f32x4 __attribute__((ext_vector_type(4)));

__device__ __forceinline__ f32x4 mfma16(bf16x8 a, bf16x8 b, f32x4 c) {
  return __builtin_amdgcn_mfma_f32_16x16x32_bf16(a, b, c, 0, 0, 0);
}

// async global->LDS 16B; LDS dest is wave-uniform base, lane l writes base+l*16.
__device__ __forceinline__ void gload16(const void* g, void* l) {
  __builtin_amdgcn_global_load_lds(
      (const __attribute__((address_space(1))) void*)g,
      (__attribute__((address_space(3))) void*)(uint32_t)(size_t)l, 16, 0, 0);
}

__device__ __forceinline__ bf16x8 cvt8(float4 a, float4 b) {
  bf16x8 r;
  r[0] = (bf16)a.x; r[1] = (bf16)a.y; r[2] = (bf16)a.z; r[3] = (bf16)a.w;
  r[4] = (bf16)b.x; r[5] = (bf16)b.y; r[6] = (bf16)b.z; r[7] = (bf16)b.w;
  return r;
}

// ---------------- merged prep: gating | convert_w | border_zero ----------------
template <int CIN, int COUT, int COUTP>
__device__ __forceinline__ void cw_one(const float* __restrict__ w,
                                       bf16* __restrict__ wp, int idx) {
  constexpr int K = 4 * CIN;
  int ic = idx & (CIN - 1);
  int t = (idx / CIN) & 3;
  int oc = (idx / K) % COUTP;
  int p = idx / (K * COUTP);
  bf16 v = (bf16)0.f;
  if (oc < COUT) {
    int py = p >> 1, px = p & 1, tyi = t >> 1, txi = t & 1;
    int ky = py == 0 ? (tyi ? 3 : 1) : (tyi ? 2 : 0);
    int kx = px == 0 ? (txi ? 3 : 1) : (txi ? 2 : 0);
    v = (bf16)w[((ic * COUT + oc) * 4 + ky) * 4 + kx];
  }
  wp[idx] = v;
}

template <int HP, int WP, int C>
__device__ __forceinline__ void bz_one(bf16* __restrict__ buf, int idx) {
  constexpr int NCELL = 2 * WP + 2 * (HP - 2);
  constexpr int C8 = C / 8;
  int c8 = idx % C8;
  int rem = idx / C8;
  int cell = rem % NCELL;
  int b = rem / NCELL;
  int y, x;
  if (cell < WP) { y = 0; x = cell; }
  else if (cell < 2 * WP) { y = HP - 1; x = cell - WP; }
  else { int r2 = cell - 2 * WP; y = 1 + (r2 >> 1); x = (r2 & 1) ? WP - 1 : 0; }
  bf16x8 z = {};
  *(bf16x8*)(buf + ((size_t)(b * HP + y) * WP + x) * C + c8 * 8) = z;
}

// Panel layout: row-group rg=b>>4 (64KB); byte rg*65536 + s*1024 + lane*16 = granule
// q=4s+(lane>>4) of row rg*16+(lane&15).
__global__ __launch_bounds__(256) void prep_kernel(
    const float* __restrict__ x, const float* __restrict__ gw,
    const float* __restrict__ gb, bf16* __restrict__ xgbP,
    float* __restrict__ gbuf,
    const float* __restrict__ w1, bf16* __restrict__ w1p,
    const float* __restrict__ w2, bf16* __restrict__ w2p,
    const float* __restrict__ w3, bf16* __restrict__ w3p,
    bf16* __restrict__ h0t, bf16* __restrict__ h1, bf16* __restrict__ h2) {
  __shared__ float xs[256];
  __shared__ float gs[8];
  const int bid = blockIdx.x, tid = threadIdx.x;
  if (bid < 256) {
    // ---- gating ----
    const int b = bid;
    xs[tid] = x[b * 256 + tid];
    __syncthreads();
    if (tid < 8) {
      float acc = gb[tid];
      for (int i = 0; i < 256; ++i) acc += xs[i] * gw[i * 8 + tid];
      gs[tid] = acc;
    }
    __syncthreads();
    if (tid == 0) {
      float m = gs[0];
      for (int l = 1; l < 8; ++l) m = fmaxf(m, gs[l]);
      float s = 0.f, e[8];
      for (int l = 0; l < 8; ++l) { e[l] = expf(gs[l] - m); s += e[l]; }
      float inv = 1.f / s;
      for (int l = 0; l < 8; ++l) gs[l] = e[l] * inv;
    }
    __syncthreads();
    if (tid < 8) gbuf[b * 8 + tid] = gs[tid];
    float xv = xs[tid];
    bf16x8 r;
#pragma unroll
    for (int j = 0; j < 8; ++j) r[j] = (bf16)(xv * gs[j]);
    size_t off = (size_t)(b >> 4) * 65536 + (size_t)(tid >> 2) * 1024 +
                 (size_t)(((tid & 3) * 16 + (b & 15)) * 16);
    *(bf16x8*)((char*)xgbP + off) = r;
  } else if (bid < 928) {
    // ---- weight transform ----
    int idx = (bid - 256) * 256 + tid;
    if (idx < 131072) cw_one<128, 64, 64>(w1, w1p, idx);
    else if (idx < 163840) cw_one<64, 32, 32>(w2, w2p, idx - 131072);
    else if (idx < 172032) cw_one<32, 3, 16>(w3, w3p, idx - 163840);
  } else {
    // ---- halo zero ----
    int idx = (bid - 928) * 256 + tid;
    if (idx < 147456) bz_one<10, 10, 128>(h0t, idx);
    else if (idx < 286720) bz_one<18, 18, 64>(h1, idx - 147456);
    else if (idx < 421888) bz_one<34, 34, 32>(h2, idx - 286720);
  }
}

// ---------------- fused ME GEMM (best-known, r13 verbatim): BM=16, 2 blocks/CU ------
// C[o,b] = bf16(pw[o,:]) . xgb[b,:] + dot(g[b],pb[o]).
// 512 blocks (2/CU) x 512 thr (8 waves). Block stages its 16 pw rows (f32->bf16
// in-register) into 64KB LDS once; ONE barrier; barrier-free K-loop: A from
// swizzled LDS, B from panel-layout xgbP (16B/lane sequential, L2-hot).
__global__ __launch_bounds__(512) void me_gemm_kernel(
    const float* __restrict__ pw, const bf16* __restrict__ xgbP,
    const float* __restrict__ pb, const float* __restrict__ gbuf,
    bf16* __restrict__ h0t) {
  __shared__ char sA[65536];
  const int tid = threadIdx.x, wv = tid >> 6, l = tid & 63;
  const int lr = l & 15, lkg = l >> 4;
  const int M0 = blockIdx.x * 16;

#pragma unroll
  for (int it = 0; it < 8; ++it) {
    int g = it * 512 + tid;
    int kt = g >> 7, rem = g & 127;
    int row = rem >> 3, ig = rem & 7;
    const float* src = pw + (size_t)(M0 + row) * 2048 + kt * 64 + ig * 8;
    float4 v0 = *(const float4*)src;
    float4 v1 = *(const float4*)(src + 4);
    int L = kt * 2048 + row * 128 + ((ig * 16) ^ ((row & 7) << 4));
    *(bf16x8*)(sA + L) = cvt8(v0, v1);
  }
  __syncthreads();

  int aoff[2];
#pragma unroll
  for (int ks = 0; ks < 2; ++ks)
    aoff[ks] = lr * 128 + (((ks * 4 + lkg) * 16) ^ ((lr & 7) << 4));

  const char* pB0 = (const char*)xgbP + (size_t)(2 * wv) * 65536 + l * 16;
  const char* pB1 = (const char*)xgbP + (size_t)(2 * wv + 1) * 65536 + l * 16;

  f32x4 acc[2] = {};
#pragma unroll 8
  for (int s = 0; s < 64; ++s) {
    const int kt = s >> 1, ks = s & 1;
    const char* base = sA + kt * 2048;
    bf16x8 a0 = *(const bf16x8*)(base + aoff[ks]);
    bf16x8 b0 = *(const bf16x8*)(pB0 + s * 1024);
    bf16x8 b1 = *(const bf16x8*)(pB1 + s * 1024);
    acc[0] = mfma16(a0, b0, acc[0]);
    acc[1] = mfma16(a0, b1, acc[1]);
  }

  float4 g0[2], g1[2];
#pragma unroll
  for (int n = 0; n < 2; ++n) {
    int b = wv * 32 + n * 16 + lr;
    g0[n] = *(const float4*)(gbuf + b * 8);
    g1[n] = *(const float4*)(gbuf + b * 8 + 4);
  }
#pragma unroll
  for (int r = 0; r < 4; ++r) {
    int o = M0 + lkg * 4 + r;
    float4 p0 = *(const float4*)(pb + o * 8);
    float4 p1 = *(const float4*)(pb + o * 8 + 4);
    int cch = o >> 6, y = (o >> 3) & 7, xx = o & 7;
#pragma unroll
    for (int n = 0; n < 2; ++n) {
      int b = wv * 32 + n * 16 + lr;
      float bias = g0[n].x * p0.x + g0[n].y * p0.y + g0[n].z * p0.z + g0[n].w * p0.w +
                   g1[n].x * p1.x + g1[n].y * p1.y + g1[n].z * p1.z + g1[n].w * p1.w;
      h0t[((size_t)(b * 10 + y + 1) * 10 + xx + 1) * 128 + cch] = (bf16)(acc[n][r] + bias);
    }
  }
}

// ---------------- conv-transpose (r3/r8-best, verbatim): split parity, WLDS ---------
template <int CIN, int H, int YB, int COUTP, int WM, int NF, int SWM,
          bool WLDS, int INIT, int WIT, bool RELU, bool F32OUT, int SIN_SZ, int SW_SZ>
__global__ __launch_bounds__(256) void convt_kernel(
    const bf16* __restrict__ in, const bf16* __restrict__ wp,
    const float* __restrict__ bias, bf16* __restrict__ out,
    float* __restrict__ fout) {
  constexpr int W = H, WROW = W + 2, ROWB = CIN * 2, GRS = ROWB / 16;
  constexpr int LGR = (GRS == 16) ? 4 : (GRS == 8) ? 3 : 2;
  constexpr int LW = (W == 8) ? 3 : (W == 16) ? 4 : 5;
  constexpr int K = 4 * CIN;
  constexpr int CHUNKS = (YB + 2) * WROW * GRS;
  constexpr int WGR = K / 8;
  __shared__ char sIn[SIN_SZ];
  __shared__ char sW[SW_SZ];

  const int tid = threadIdx.x, wv = tid >> 6, l = tid & 63;
  const int nyb = H / YB;
  const int img = blockIdx.x / nyb, y0 = (blockIdx.x % nyb) * YB;
  const int p = blockIdx.y, py = p >> 1, px = p & 1;

#pragma unroll
  for (int it = 0; it < INIT; ++it) {
    int t = it * 256 + tid;
    int tc = t < CHUNKS ? t : CHUNKS - 1;
    int pix = tc >> LGR, cc = tc & (GRS - 1);
    int ly = pix / WROW, lx = pix % WROW;
    int sb = (cc * 16) ^ ((pix & SWM) << 4);
    gload16(in + ((size_t)((img * (H + 2) + y0 + ly) * (W + 2) + lx)) * CIN + (sb >> 1),
            sIn + it * 4096 + wv * 1024);
  }
  if constexpr (WLDS) {
#pragma unroll
    for (int it = 0; it < WIT; ++it) {
      int t = it * 256 + tid;
      int oc = t / WGR, cc = t % WGR;
      int sb = (cc * 16) ^ ((oc & 7) << 4);
      gload16(wp + (size_t)(p * COUTP + oc) * K + (sb >> 1), sW + it * 4096 + wv * 1024);
    }
  }
  __syncthreads();

  const int lr = l & 15, lkg = l >> 4;
  const int wm = wv & (WM - 1), wn = wv / WM;
  int pcen[2];
#pragma unroll
  for (int m = 0; m < 2; ++m) {
    int r = wm * 32 + m * 16 + lr;
    pcen[m] = ((r >> LW) + 1) * WROW + (r & (W - 1)) + 1;
  }

  f32x4 acc[2][NF] = {};
#pragma unroll 4
  for (int kk = 0; kk < K; kk += 32) {
    const int t4 = kk / CIN;
    const int tyi = t4 >> 1, txi = t4 & 1;
    const int dy = (py == 0) ? (tyi ? -1 : 0) : (tyi ? 0 : 1);
    const int dx = (px == 0) ? (txi ? -1 : 0) : (txi ? 0 : 1);
    const int icb = (kk % CIN) * 2 + lkg * 16;
    bf16x8 av[2], bv[NF];
#pragma unroll
    for (int m = 0; m < 2; ++m) {
      int pixd = pcen[m] + dy * WROW + dx;
      av[m] = *(const bf16x8*)(sIn + pixd * ROWB + (icb ^ ((pixd & SWM) << 4)));
    }
#pragma unroll
    for (int n = 0; n < NF; ++n) {
      int oc = (wn * NF + n) * 16 + lr;
      if constexpr (WLDS) {
        int kb = kk * 2 + lkg * 16;
        bv[n] = *(const bf16x8*)(sW + oc * (K * 2) + (kb ^ ((oc & 7) << 4)));
      } else {
        bv[n] = *(const bf16x8*)(wp + (size_t)(p * COUTP + oc) * K + kk + lkg * 8);
      }
    }
#pragma unroll
    for (int m = 0; m < 2; ++m)
#pragma unroll
      for (int n = 0; n < NF; ++n) acc[m][n] = mfma16(av[m], bv[n], acc[m][n]);
  }

#pragma unroll
  for (int m = 0; m < 2; ++m)
#pragma unroll
    for (int r4 = 0; r4 < 4; ++r4) {
      int r = wm * 32 + m * 16 + lkg * 4 + r4;
      int yy = r >> LW, xx = r & (W - 1);
      int oy = 2 * (y0 + yy) + py, ox = 2 * xx + px;
#pragma unroll
      for (int n = 0; n < NF; ++n) {
        int oc = (wn * NF + n) * 16 + lr;
        float v = acc[m][n][r4];
        if constexpr (F32OUT) {
          if (oc < 3) fout[((size_t)(img * 3 + oc) * (2 * H) + oy) * (2 * H) + ox] = v + bias[oc];
        } else {
          v += bias[oc];
          if constexpr (RELU) v = fmaxf(v, 0.f);
          out[((size_t)(img * (2 * H + 2) + oy + 1) * (2 * H + 2) + ox + 1) * COUTP + oc] = (bf16)v;
        }
      }
    }
}

// ---------------- launch ----------------
extern "C" void kernel_launch(void* const* d_in, const int* in_sizes, int n_in,
                              void* d_out, int out_size, void* d_ws, size_t ws_size,
                              hipStream_t stream) {
  const float* x  = (const float*)d_in[0];
  const float* gw = (const float*)d_in[1];
  const float* gb = (const float*)d_in[2];
  const float* pw = (const float*)d_in[3];
  const float* pb = (const float*)d_in[4];
  const float* w1 = (const float*)d_in[5];
  const float* b1 = (const float*)d_in[6];
  const float* w2 = (const float*)d_in[7];
  const float* b2 = (const float*)d_in[8];
  const float* w3 = (const float*)d_in[9];
  const float* b3 = (const float*)d_in[10];
  float* outp = (float*)d_out;

  char* ws = (char*)d_ws;
  bf16*  xgbP = (bf16*)(ws + 0);          // 1,048,576 (panel layout)
  float* gbuf = (float*)(ws + 1048576);   // 8,192
  bf16*  h0t  = (bf16*)(ws + 1056768);    // 6,553,600
  bf16*  w1p  = (bf16*)(ws + 7610368);    // 262,144
  bf16*  h1   = (bf16*)(ws + 7872512);    // 10,616,832
  bf16*  w2p  = (bf16*)(ws + 18489344);   // 65,536
  bf16*  h2   = (bf16*)(ws + 18554880);   // 18,939,904
  bf16*  w3p  = (bf16*)(ws + 37494784);   // 16,384

  prep_kernel<<<2576, 256, 0, stream>>>(x, gw, gb, xgbP, gbuf,
                                        w1, w1p, w2, w2p, w3, w3p, h0t, h1, h2);

  me_gemm_kernel<<<512, 512, 0, stream>>>(pw, xgbP, pb, gbuf, h0t);

  // conv1: split parity, weights direct (L2)
  convt_kernel<128, 8, 8, 64, 2, 2, 7, false, 7, 0, true, false, 28672, 16>
      <<<dim3(256, 4), 256, 0, stream>>>(h0t, w1p, b1, h1, nullptr);
  // conv2: split parity, weights in LDS
  convt_kernel<64, 16, 8, 32, 4, 2, 7, true, 6, 4, true, false, 24576, 16384>
      <<<dim3(512, 4), 256, 0, stream>>>(h1, w2p, b2, h2, nullptr);
  // conv3: split parity, weights in LDS, f32 out
  convt_kernel<32, 32, 4, 16, 4, 1, 3, true, 4, 1, false, true, 16384, 4096>
      <<<dim3(2048, 4), 256, 0, stream>>>(h2, w3p, b3, nullptr, outp);
}